// Round 1
// 777.907 us; speedup vs baseline: 1.3233x; 1.3233x over previous
//
#include <hip/hip_runtime.h>

typedef unsigned short u16;
typedef unsigned int u32;
typedef __bf16 bf16x8 __attribute__((ext_vector_type(8)));
typedef float f32x4 __attribute__((ext_vector_type(4)));

#define S_LEN 1024
#define D_MODEL 768
#define N_CONV 19
#define BORROW_ROW 1888   // global pi rows [1888,2048) are scratch until fixup

__device__ __forceinline__ float bf2f(u16 h) {
    u32 u = ((u32)h) << 16;
    return __builtin_bit_cast(float, u);
}
__device__ __forceinline__ u16 f2bf(float f) {
    u32 u = __builtin_bit_cast(u32, f);
    u32 r = (u + 0x7fffu + ((u >> 16) & 1u)) >> 16;
    return (u16)r;
}

// ---------------------------------------------------------------------------
// K0: dtype-robust input conversion -> bf16. Probe gamma (ones): bf16 ->
// u16[0]==0x3F80; f32 -> u16[0]==0x0000. Device-side branch (capture-safe).
// Ordering is chosen so Wq|Wk and Wv|Wa|Wb|Wr are contiguous (concat GEMMs).
// ---------------------------------------------------------------------------
struct ConvArgs {
    const void* src[N_CONV];
    int n[N_CONV];
    int off[N_CONV];
};

__global__ __launch_bounds__(256) void convert_kernel(ConvArgs a, u16* __restrict__ dst,
                                                      const u16* __restrict__ probe) {
    bool isbf = (probe[0] == 0x3F80u);
    int inp = blockIdx.y;
    int n = a.n[inp];
    u16* d = dst + a.off[inp];
    const u16* s16 = (const u16*)a.src[inp];
    const float* s32 = (const float*)a.src[inp];
    int base = blockIdx.x * 1024 + threadIdx.x;
#pragma unroll
    for (int t = 0; t < 4; ++t) {
        int idx = base + t * 256;
        if (idx < n) d[idx] = isbf ? s16[idx] : f2bf(s32[idx]);
    }
}

// ---------------------------------------------------------------------------
// K1: precompute emb2bf (64x32 bf16, M^T folded), w4 (64x4 f32)
// ---------------------------------------------------------------------------
__global__ __launch_bounds__(256) void precomp_kernel(
    const u16* __restrict__ vemb, const u16* __restrict__ vgates,
    const u16* __restrict__ Wspec, const u16* __restrict__ adj,
    const u16* __restrict__ spec, const u16* __restrict__ ap,
    const u16* __restrict__ bd, const u16* __restrict__ rs,
    u16* __restrict__ emb2bf, float* __restrict__ w4)
{
    __shared__ float emb[64 * 32];
    __shared__ float gred[256];
    int tid = threadIdx.x;
    for (int p = 0; p < 8; ++p) {
        int idx = tid + p * 256;
        int v = idx >> 5, d = idx & 31;
        float acc = bf2f(vemb[idx]);
        for (int t = 0; t < 6; ++t)
            acc += 0.1f * bf2f(spec[v * 6 + t]) * bf2f(Wspec[d * 6 + t]);
        emb[idx] = acc;
    }
    __syncthreads();
    for (int p = 0; p < 8; ++p) {
        int idx = tid + p * 256;
        int u = idx >> 5, d = idx & 31;
        float a2 = 0.f;
        for (int v = 0; v < 64; ++v)
            a2 += bf2f(adj[v * 64 + u]) * emb[v * 32 + d];
        emb2bf[idx] = f2bf(emb[idx] + 0.1f * a2);
    }
    int u = tid >> 2, qp = tid & 3;
    float acc = 0.f;
    for (int c = 0; c < 192; ++c) {
        float x = bf2f(vgates[u * 768 + qp * 192 + c]);
        acc += 1.f / (1.f + __expf(-x));
    }
    gred[tid] = acc;
    __syncthreads();
    if (qp == 0) {
        float gm = (gred[tid] + gred[tid + 1] + gred[tid + 2] + gred[tid + 3]) * (1.f / 768.f);
        w4[u * 4 + 0] = gm;
        w4[u * 4 + 1] = bf2f(ap[u]);
        w4[u * 4 + 2] = bf2f(bd[u]);
        w4[u * 4 + 3] = bf2f(rs[u]);
    }
}

// ---------------------------------------------------------------------------
// Generic MFMA GEMM: C = A(MxK) @ B(NxK)^T, bf16 in, f32 accum.
// Block 256 = 4 waves; block tile 64x64; wave tile 32x32 (2x2 MFMA 16x16x32).
// ---------------------------------------------------------------------------
template <int OUT_BF16>
__global__ __launch_bounds__(256) void gemm_abt(
    int M, int N, int K,
    const u16* __restrict__ A, long long sA,
    const u16* __restrict__ B, long long sB,
    void* __restrict__ Cout, long long sC, int ldc)
{
    int bz = blockIdx.z;
    A += (long long)bz * sA;
    B += (long long)bz * sB;
    long long cb = (long long)bz * sC;

    int lane = threadIdx.x & 63;
    int wave = threadIdx.x >> 6;
    int quad = lane >> 4, l16 = lane & 15;
    int m0 = blockIdx.x * 64 + (wave >> 1) * 32;
    int n0 = blockIdx.y * 64 + (wave & 1) * 32;

    f32x4 acc[2][2] = {};
    for (int k0 = 0; k0 < K; k0 += 32) {
        bf16x8 a[2], b[2];
#pragma unroll
        for (int mi = 0; mi < 2; ++mi) {
            int r = m0 + mi * 16 + l16;
            r = r < M ? r : M - 1;
            a[mi] = *reinterpret_cast<const bf16x8*>(A + (long long)r * K + k0 + quad * 8);
        }
#pragma unroll
        for (int ni = 0; ni < 2; ++ni) {
            int r = n0 + ni * 16 + l16;
            r = r < N ? r : N - 1;
            b[ni] = *reinterpret_cast<const bf16x8*>(B + (long long)r * K + k0 + quad * 8);
        }
#pragma unroll
        for (int mi = 0; mi < 2; ++mi)
#pragma unroll
            for (int ni = 0; ni < 2; ++ni)
                acc[mi][ni] = __builtin_amdgcn_mfma_f32_16x16x32_bf16(a[mi], b[ni], acc[mi][ni], 0, 0, 0);
    }
    // C/D layout: col = lane&15, row = quad*4 + reg
#pragma unroll
    for (int mi = 0; mi < 2; ++mi)
#pragma unroll
        for (int ni = 0; ni < 2; ++ni) {
            int col = n0 + ni * 16 + l16;
#pragma unroll
            for (int r = 0; r < 4; ++r) {
                int row = m0 + mi * 16 + quad * 4 + r;
                if (row < M && col < N) {
                    float v = acc[mi][ni][r];
                    if (OUT_BF16)
                        ((u16*)Cout)[cb + (long long)row * ldc + col] = f2bf(v);
                    else
                        ((float*)Cout)[cb + (long long)row * ldc + col] = v;
                }
            }
        }
}

// ---------------------------------------------------------------------------
// Fused E: combb[b][i][c] = scl0[i]*(wpl0 @ VxT^T)[i][c] + sclg[i]*(wplg @ VmT^T)[i][c]
// VX2 = [Wv;Wa;Wb;Wr] @ x^T  -> rows 0..767 = scalar V, rows 768+c = modal row c.
// Plane g = c >> 8 is uniform per 64-col block. Replaces E1 + 3x E2.
// ---------------------------------------------------------------------------
__global__ __launch_bounds__(256) void efused_kernel(
    const u16* __restrict__ wpl, const u16* __restrict__ VX2,
    const float* __restrict__ scl, u16* __restrict__ combb)
{
    const int S = S_LEN;
    const long long SS = (long long)S * S;
    int b = blockIdx.z;
    int lane = threadIdx.x & 63;
    int wave = threadIdx.x >> 6;
    int quad = lane >> 4, l16 = lane & 15;
    int m0 = blockIdx.x * 64 + (wave >> 1) * 32;
    int n0 = blockIdx.y * 64 + (wave & 1) * 32;
    int g = (blockIdx.y * 64) >> 8;

    const u16* A0 = wpl + (long long)b * 4 * SS;
    const u16* Ag = A0 + (long long)(1 + g) * SS;
    const u16* B = VX2 + (long long)b * 1536 * S;

    f32x4 acc0[2][2] = {}, accg[2][2] = {};
    for (int k0 = 0; k0 < S; k0 += 32) {
        bf16x8 a0[2], ag[2], b0[2], bg[2];
#pragma unroll
        for (int mi = 0; mi < 2; ++mi) {
            long long r = m0 + mi * 16 + l16;
            a0[mi] = *reinterpret_cast<const bf16x8*>(A0 + r * S + k0 + quad * 8);
            ag[mi] = *reinterpret_cast<const bf16x8*>(Ag + r * S + k0 + quad * 8);
        }
#pragma unroll
        for (int ni = 0; ni < 2; ++ni) {
            long long c = n0 + ni * 16 + l16;
            b0[ni] = *reinterpret_cast<const bf16x8*>(B + c * S + k0 + quad * 8);
            bg[ni] = *reinterpret_cast<const bf16x8*>(B + (768 + c) * S + k0 + quad * 8);
        }
#pragma unroll
        for (int mi = 0; mi < 2; ++mi)
#pragma unroll
            for (int ni = 0; ni < 2; ++ni) {
                acc0[mi][ni] = __builtin_amdgcn_mfma_f32_16x16x32_bf16(a0[mi], b0[ni], acc0[mi][ni], 0, 0, 0);
                accg[mi][ni] = __builtin_amdgcn_mfma_f32_16x16x32_bf16(ag[mi], bg[ni], accg[mi][ni], 0, 0, 0);
            }
    }
    const float* s0p = scl + (long long)(b * 4) * S;
    const float* sgp = scl + (long long)(b * 4 + 1 + g) * S;
#pragma unroll
    for (int mi = 0; mi < 2; ++mi)
#pragma unroll
        for (int ni = 0; ni < 2; ++ni) {
            int col = n0 + ni * 16 + l16;
#pragma unroll
            for (int r = 0; r < 4; ++r) {
                int row = m0 + mi * 16 + quad * 4 + r;
                float v = s0p[row] * acc0[mi][ni][r] + sgp[row] * accg[mi][ni][r];
                combb[(long long)b * S * D_MODEL + (long long)row * D_MODEL + col] = f2bf(v);
            }
        }
}

// ---------------------------------------------------------------------------
// Stage C (MFMA): scores + softmax + pi + weight planes + denominators.
// One block per (b,i). Per wave-tile: 16 j x 64 u via 4x mfma_16x16x32_bf16
// with A = emb2 (u rows), B = (k .* q) bf16 (j rows). Lane (quad,l16) holds
// s[u = mi*16+quad*4+r][j = j0+l16]; softmax over u = 16 in-lane values +
// shfl_xor(16/32) across quads. pi stores are 4x float4, 64B-contiguous/row.
// MODE 0: all rows -> wpl/scales; pi only for grow < BORROW_ROW.
// MODE 1: fixup -- pi only, rows >= BORROW_ROW. Runs LAST.
// ---------------------------------------------------------------------------
template <int MODE>
__global__ __launch_bounds__(256) void stage_c_kernel(
    const float* __restrict__ qk,       // [2048][64]: q cols 0-31, k cols 32-63
    const u16* __restrict__ emb2bf,     // [64][32] bf16
    const float* __restrict__ w4,       // [64][4]
    float* __restrict__ pi_out, u16* __restrict__ wpl, float* __restrict__ scales)
{
    const int S = S_LEN;
    const long long SS = (long long)S * S;
    int grow = MODE ? (BORROW_ROW + (int)blockIdx.x) : (int)blockIdx.x;
    int b = grow >> 10, i = grow & 1023;
    bool write_pi = MODE ? true : (grow < BORROW_ROW);
    int tid = threadIdx.x;
    int lane = tid & 63, wave = tid >> 6;
    int quad = lane >> 4, l16 = lane & 15;

    // emb2 A-fragments (row = u = mi*16 + l16, k-slice = quad*8..+8)
    bf16x8 afrag[4];
#pragma unroll
    for (int mi = 0; mi < 4; ++mi)
        afrag[mi] = *reinterpret_cast<const bf16x8*>(emb2bf + (mi * 16 + l16) * 32 + quad * 8);

    // q slice for this lane's k-range
    const float* qp = qk + (long long)grow * 64 + quad * 8;
    f32x4 q0 = *(const f32x4*)qp;
    f32x4 q1 = *(const f32x4*)(qp + 4);

    // w4 rows for this lane's u-set (u = mi*16 + quad*4 + r) -- block-invariant
    f32x4 w4r[4][4];
    if (MODE == 0) {
#pragma unroll
        for (int mi = 0; mi < 4; ++mi)
#pragma unroll
            for (int r = 0; r < 4; ++r)
                w4r[mi][r] = *(const f32x4*)(w4 + (mi * 16 + quad * 4 + r) * 4);
    }

    float* pirow = pi_out + (long long)grow * (S * 64);
    const float* kb = qk + ((long long)(b << 10)) * 64;
    u16* wrow = wpl + (long long)(b * 4 + quad) * SS + (long long)i * S;

    float rs = 0.f;

    for (int t = wave; t < 64; t += 4) {
        int j0 = t << 4;
        int jl = j0 + l16;
        float* pdst = pirow + (long long)jl * 64 + quad * 4;
        if (j0 > i) {
            if (write_pi) {
                f32x4 z = {0.f, 0.f, 0.f, 0.f};
#pragma unroll
                for (int mi = 0; mi < 4; ++mi) *(f32x4*)(pdst + mi * 16) = z;
            }
            if (MODE == 0) wrow[jl] = 0;
            continue;
        }
        // B-fragment: (k .* q) for row j = jl, k-slice quad*8..+8, in bf16
        const float* kp = kb + (long long)jl * 64 + 32 + quad * 8;
        f32x4 k0 = *(const f32x4*)kp;
        f32x4 k1 = *(const f32x4*)(kp + 4);
        bf16x8 bfr;
#pragma unroll
        for (int d = 0; d < 4; ++d) bfr[d] = (__bf16)(k0[d] * q0[d]);
#pragma unroll
        for (int d = 0; d < 4; ++d) bfr[4 + d] = (__bf16)(k1[d] * q1[d]);

        f32x4 acc[4];
#pragma unroll
        for (int mi = 0; mi < 4; ++mi) {
            f32x4 z = {0.f, 0.f, 0.f, 0.f};
            acc[mi] = __builtin_amdgcn_mfma_f32_16x16x32_bf16(afrag[mi], bfr, z, 0, 0, 0);
        }
        // row max over all 64 u (16 in-lane + cross-quad butterfly)
        float M = acc[0][0];
#pragma unroll
        for (int mi = 0; mi < 4; ++mi)
#pragma unroll
            for (int r = 0; r < 4; ++r) M = fmaxf(M, acc[mi][r]);
        M = fmaxf(M, __shfl_xor(M, 16));
        M = fmaxf(M, __shfl_xor(M, 32));
        // exp, denom, and w4-weighted partial dots
        float sum = 0.f;
        f32x4 pg = {0.f, 0.f, 0.f, 0.f};
        float e[4][4];
#pragma unroll
        for (int mi = 0; mi < 4; ++mi)
#pragma unroll
            for (int r = 0; r < 4; ++r) {
                float ev = __expf(acc[mi][r] - M);
                e[mi][r] = ev;
                sum += ev;
                if (MODE == 0) pg += w4r[mi][r] * ev;
            }
        sum += __shfl_xor(sum, 16);
        sum += __shfl_xor(sum, 32);
        if (MODE == 0) {
#pragma unroll
            for (int c = 0; c < 4; ++c) {
                pg[c] += __shfl_xor(pg[c], 16);
                pg[c] += __shfl_xor(pg[c], 32);
            }
        }
        float inv = 1.0f / sum;
        float sc = (jl <= i) ? inv : 0.f;   // causal mask: whole lane's j
        if (write_pi) {
#pragma unroll
            for (int mi = 0; mi < 4; ++mi) {
                f32x4 pv;
#pragma unroll
                for (int r = 0; r < 4; ++r) pv[r] = e[mi][r] * sc;
                *(f32x4*)(pdst + mi * 16) = pv;
            }
        }
        if (MODE == 0) {
            float a = pg[quad] * sc;        // lane's quad owns plane `quad`
            wrow[jl] = f2bf(a);
            rs += a;
        }
    }
    if (MODE == 1) return;
    // reduce rs over the 16 l16-lanes within each (wave, quad)
    rs += __shfl_xor(rs, 1);
    rs += __shfl_xor(rs, 2);
    rs += __shfl_xor(rs, 4);
    rs += __shfl_xor(rs, 8);
    __shared__ float sred[16];
    if (l16 == 0) sred[wave * 4 + quad] = rs;
    __syncthreads();
    if (tid < 4) {
        float R = sred[tid] + sred[4 + tid] + sred[8 + tid] + sred[12 + tid];
        float scv;
        if (tid == 0) {
            scv = 1.f / (R + 1e-8f);
        } else {
            float T1 = R + 1e-8f;
            float T2 = R / T1 + 1e-8f;
            scv = 1.f / (T1 * T2);
        }
        scales[(b * 4 + tid) * S + i] = scv;
    }
}

// ---------------------------------------------------------------------------
// LayerNorm: resf(bf16) + bo -> normed f32
// ---------------------------------------------------------------------------
__global__ __launch_bounds__(256) void ln_kernel(
    const u16* __restrict__ resf, const u16* __restrict__ bo,
    const u16* __restrict__ gamma, const u16* __restrict__ beta,
    float* __restrict__ out)
{
    int row = blockIdx.x;
    int tid = threadIdx.x;
    __shared__ float red[256];
    float x[3];
#pragma unroll
    for (int p = 0; p < 3; ++p) {
        int c = tid + p * 256;
        x[p] = bf2f(resf[(long long)row * 768 + c]) + bf2f(bo[c]);
    }
    float ls = x[0] + x[1] + x[2];
    red[tid] = ls;
    __syncthreads();
    for (int st = 128; st > 0; st >>= 1) {
        if (tid < st) red[tid] += red[tid + st];
        __syncthreads();
    }
    float mu = red[0] * (1.f / 768.f);
    __syncthreads();
    float ls2 = 0.f;
#pragma unroll
    for (int p = 0; p < 3; ++p) {
        float d = x[p] - mu;
        ls2 += d * d;
    }
    red[tid] = ls2;
    __syncthreads();
    for (int st = 128; st > 0; st >>= 1) {
        if (tid < st) red[tid] += red[tid + st];
        __syncthreads();
    }
    float var = red[0] * (1.f / 768.f);
    float rstd = rsqrtf(var + 1e-5f);
#pragma unroll
    for (int p = 0; p < 3; ++p) {
        int c = tid + p * 256;
        out[(long long)row * 768 + c] = (x[p] - mu) * rstd * bf2f(gamma[c]) + bf2f(beta[c]);
    }
}

// ---------------------------------------------------------------------------
extern "C" void kernel_launch(void* const* d_in, const int* in_sizes, int n_in,
                              void* d_out, int out_size, void* d_ws, size_t ws_size,
                              hipStream_t stream)
{
    const long long S = S_LEN, D = D_MODEL, BS = 2 * S;

    float* out_norm = (float*)d_out;
    float* out_pi   = out_norm + BS * D;

    // --- small buffers in d_ws (~0.6 MB total) ---
    char* wsp = (char*)d_ws;
    size_t woff = 0;
    auto walloc = [&](size_t bytes) -> void* {
        void* p = wsp + woff;
        woff = (woff + bytes + 255) & ~(size_t)255;
        return p;
    };
    u16*   emb2bf = (u16*)walloc(64 * 32 * 2);
    float* w4     = (float*)walloc(64 * 4 * 4);
    float* qkbuf  = (float*)walloc(BS * 64 * 4);     // [row][q0..31 | k0..31]
    float* scl    = (float*)walloc(2 * 4 * S * 4);   // [b][plane][i]

    // --- bulk buffers borrowed from pi rows [BORROW_ROW, 2048):
    //     160 rows x 65536 f32 x 4B = 41.9 MB capacity ---
    u16* borrow = (u16*)(out_pi + (long long)BORROW_ROW * S * 64);
    long long boff = 0;
    auto balloc = [&](long long elems) -> u16* {
        u16* p = borrow + boff;
        boff += (elems + 127) & ~(long long)127;
        return p;
    };

    // conversion region: 19 used inputs (skip mask at index 1).
    // Order: x, Wq, Wk, Wv, Wa, Wb, Wr, then the rest -- so [Wq;Wk] (64x768)
    // and [Wv;Wa;Wb;Wr] (1536x768) are contiguous (all sizes %128 == 0).
    static const int cidx[N_CONV] = {0, 2, 3, 6, 8, 9, 10, 4, 5, 7, 11, 12, 13, 14, 15, 16, 17, 18, 19};
    ConvArgs ca;
    int coff[N_CONV];
    {
        int running = 0;
        for (int t = 0; t < N_CONV; ++t) {
            ca.src[t] = d_in[cidx[t]];
            ca.n[t] = in_sizes[cidx[t]];
            coff[t] = running;
            ca.off[t] = running;
            running += (in_sizes[cidx[t]] + 127) & ~127;
        }
        (void)balloc(running);  // conv region = start of borrow
    }
    u16* conv = borrow;
    const u16* xb      = conv + coff[0];
    const u16* Wqkb    = conv + coff[1];   // 64 x 768
    const u16* WvAllb  = conv + coff[3];   // 1536 x 768
    const u16* vembb   = conv + coff[7];
    const u16* vgatesb = conv + coff[8];
    const u16* Wspecb  = conv + coff[9];
    const u16* Wob     = conv + coff[10];
    const u16* bob     = conv + coff[11];
    const u16* gammab  = conv + coff[12];
    const u16* betab   = conv + coff[13];
    const u16* adjb    = conv + coff[14];
    const u16* specb   = conv + coff[15];
    const u16* apb     = conv + coff[16];
    const u16* bdb     = conv + coff[17];
    const u16* rsb     = conv + coff[18];

    u16* VX2   = balloc(2 * 1536 * S);    // [b][1536][1024] bf16 (V rows | modal rows)
    u16* combb = balloc(BS * D);          // combined (scalar+modal), bf16
    u16* wpl   = balloc(2 * 4 * S * S);   // [b][plane][i][j] bf16
    u16* resf  = balloc(BS * D);          // pre-LN result, bf16
    // borrowed total ~36.3 MB <= 41.9 MB  [ok]

    // K0: convert inputs to bf16 (or copy-through if already bf16)
    convert_kernel<<<dim3(1536, N_CONV), dim3(256), 0, stream>>>(ca, conv, (const u16*)d_in[13]);

    precomp_kernel<<<dim3(1), dim3(256), 0, stream>>>(
        vembb, vgatesb, Wspecb, adjb, specb, apb, bdb, rsb, emb2bf, w4);

    // qk = x @ [Wq;Wk]^T  (f32, [2048][64], lives in d_ws until fixup)
    gemm_abt<0><<<dim3(32, 1, 1), 256, 0, stream>>>(
        2048, 64, 768, xb, 0, Wqkb, 0, (void*)qkbuf, 0, 64);

    // VX2[b] = [Wv;Wa;Wb;Wr] @ x[b]^T  (1536 x 1024, bf16) -- one launch, 768 blocks
    gemm_abt<1><<<dim3(24, 16, 2), 256, 0, stream>>>(
        1536, 1024, 768, WvAllb, 0, xb, S * D, (void*)VX2, 1536 * S, 1024);

    // fused scores/softmax/pi/weights (pi skipped for borrowed rows)
    stage_c_kernel<0><<<dim3(2048), dim3(256), 0, stream>>>(
        qkbuf, emb2bf, w4, out_pi, wpl, scl);

    // fused E: combb = scl0*(wpl0 @ V^T) + sclg*(wplg @ Vm^T)
    efused_kernel<<<dim3(16, 12, 2), 256, 0, stream>>>(wpl, VX2, scl, combb);

    // F: resf = combb @ Wo^T  (bf16)
    gemm_abt<1><<<dim3(32, 12, 1), 256, 0, stream>>>(
        2048, 768, 768, combb, 0, Wob, 0, (void*)resf, 0, 768);

    // LN -> normed f32 (last reader of the borrowed region)
    ln_kernel<<<dim3(2048), dim3(256), 0, stream>>>(resf, bob, gammab, betab, out_norm);

    // fixup: write pi (f32) for the 160 borrowed rows (scratch no longer needed)
    stage_c_kernel<1><<<dim3(2048 - BORROW_ROW), dim3(256), 0, stream>>>(
        qkbuf, emb2bf, w4, out_pi, wpl, scl);
}